// Round 1
// baseline (329.027 us; speedup 1.0000x reference)
//
#include <hip/hip_runtime.h>
#include <hip/hip_bf16.h>

// Problem constants
#define NB 512     // batch
#define NP 1152    // primary capsules
#define NC 10      // digit capsules
#define ND 16      // output capsule dim
#define NI 8       // input capsule dim

constexpr int K_B    = 2;                // b's per lane (register loop)
constexpr int B_TILE = 4 * 4 * K_B;      // 32 b per block (4 waves x 4 bsub x K_B)
constexpr int P_TILE = 8;                // p's per block, LDS tile 40KB
constexpr int NBLK_B = NB / B_TILE;      // 16
constexpr int NBLK_P = NP / P_TILE;      // 144
constexpr int SVD = NB * NC * ND;        // 81920
constexpr int W_TILE_BYTES = P_TILE * NC * ND * NI * 4;   // 40960

constexpr float LOG2E = 1.4426950408889634f;

typedef float v2f __attribute__((ext_vector_type(2)));

// 16-lane all-reduce sum via DPP (quad_perm xor1, xor2; row_ror 4, 8).
// Pure VALU. Result broadcast to all 16 lanes of the row.
__device__ __forceinline__ float red16_dpp(float v) {
    int t;
    t = __builtin_amdgcn_update_dpp(0, __float_as_int(v), 0xB1, 0xF, 0xF, true); // xor1
    v += __int_as_float(t);
    t = __builtin_amdgcn_update_dpp(0, __float_as_int(v), 0x4E, 0xF, 0xF, true); // xor2
    v += __int_as_float(t);
    t = __builtin_amdgcn_update_dpp(0, __float_as_int(v), 0x124, 0xF, 0xF, true); // row_ror:4
    v += __int_as_float(t);
    t = __builtin_amdgcn_update_dpp(0, __float_as_int(v), 0x128, 0xF, 0xF, true); // row_ror:8
    v += __int_as_float(t);
    return v;
}

// One routing pass. 4 waves/block; each wave stages one LDS quarter, ALL waves
// read all 8 p's for their own 8 b's (wave*8 + k*4 + bsub). Lane = (bsub 2b | d 4b).
// LDS swizzle involution: S(A) = A ^ (bit7(A)<<4) ^ (bit8(A)<<5).
// Softmax: no max-subtraction (logits bounded |lg| <~ 35 << 127 exp2 range),
// 1/ln2 folded into vr, c-loop packed into v_pk_* pairs, v_rcp for 1/sum.
// x loads for pp+1 issued right after the dot phase (hide under softmax VALU).
// PASS 0: coup = 0.1;  PASS 1: logits = u.v0;  PASS 2: logits = u.(v0+v1)
template<int PASS>
__global__ __launch_bounds__(256, 3)
void caps_pass(const float* __restrict__ x,    // [NB, NP, NI]
               const float* __restrict__ w,    // [NP, NC, ND, NI]
               const float* __restrict__ v0,   // [NB, NC, ND]
               const float* __restrict__ v1,   // [NB, NC, ND]
               float* __restrict__ s_out)      // [NB, NC, ND]
{
    __shared__ __align__(16) float w_lds[W_TILE_BYTES / 4];   // 40KB

    const int tid  = threadIdx.x;
    const int lane = tid & 63;
    const int wave = tid >> 6;           // 0..3
    const int d    = lane & 15;
    const int bsub = lane >> 4;          // 0..3
    const int pblk = blockIdx.x % NBLK_P;
    const int bblk = blockIdx.x / NBLK_P;
    const int p0   = pblk * P_TILE;

    // ---- stage W tile: each wave loads one 10KB quarter (16B/lane, linear dest) ----
    {
        const uint8_t* wsrc = (const uint8_t*)w + (size_t)pblk * W_TILE_BYTES;
        const int lane_src = (lane << 4) ^ ((lane & 8) << 1) ^ ((lane & 16) << 1);
        #pragma unroll
        for (int j = 0; j < 10; ++j) {
            const int off = wave * 10240 + j * 1024;
            __builtin_amdgcn_global_load_lds(
                (const __attribute__((address_space(1))) void*)(wsrc + off + lane_src),
                (__attribute__((address_space(3))) void*)((uint8_t*)w_lds + off),
                16, 0, 0);
        }
    }

    int bidx[K_B];
    #pragma unroll
    for (int k = 0; k < K_B; ++k) bidx[k] = bblk * B_TILE + wave * 8 + k * 4 + bsub;

    // x for pp=0: issue now so it overlaps the W staging drain.
    v2f xv[K_B][4];
    #pragma unroll
    for (int k = 0; k < K_B; ++k) {
        const float4* xq = reinterpret_cast<const float4*>(
            x + ((size_t)bidx[k] * NP + p0) * NI);
        const float4 a = xq[0];
        const float4 b = xq[1];
        xv[k][0] = v2f{a.x, a.y};
        xv[k][1] = v2f{a.z, a.w};
        xv[k][2] = v2f{b.x, b.y};
        xv[k][3] = v2f{b.z, b.w};
    }

    // v (v0, or v0+v1 for pass 2), pre-scaled by log2(e) — loop-invariant over p
    v2f vr2[K_B][NC / 2];
    if (PASS >= 1) {
        #pragma unroll
        for (int k = 0; k < K_B; ++k)
            #pragma unroll
            for (int c = 0; c < NC; ++c) {
                float vv = v0[(bidx[k] * NC + c) * ND + d];
                if (PASS == 2) vv += v1[(bidx[k] * NC + c) * ND + d];
                vr2[k][c >> 1][c & 1] = vv * LOG2E;
            }
    }

    v2f sacc2[K_B][NC / 2];
    #pragma unroll
    for (int k = 0; k < K_B; ++k)
        #pragma unroll
        for (int c2 = 0; c2 < NC / 2; ++c2) sacc2[k][c2] = v2f{0.0f, 0.0f};

    // swizzled read offset for W[pp,c,d,0:4]: A = d*32 -> A ^ (bit2(d)<<4) ^ (bit3(d)<<5).
    const int lane_rd = (d << 5) ^ ((d & 4) << 2) ^ ((d & 8) << 2);

    asm volatile("s_waitcnt vmcnt(0)" ::: "memory");   // staging (and x) complete
    __syncthreads();                                   // all quarters visible to all waves

    for (int pp = 0; pp < P_TILE; ++pp) {
        // ---- dot phase: u_hat for this p (consumes xv) ----
        v2f uh2[K_B][NC / 2];
        #pragma unroll
        for (int c = 0; c < NC; ++c) {
            const uint8_t* pb = (const uint8_t*)w_lds + pp * 5120 + c * 512;
            const float4 wa = *(const float4*)(pb + lane_rd);          // W[p,c,d,0:4]
            const float4 wb = *(const float4*)(pb + (lane_rd ^ 16));   // W[p,c,d,4:8]
            const v2f w01{wa.x, wa.y}, w23{wa.z, wa.w};
            const v2f w45{wb.x, wb.y}, w67{wb.z, wb.w};
            #pragma unroll
            for (int k = 0; k < K_B; ++k) {
                v2f acc = w01 * xv[k][0];                              // v_pk_mul_f32
                acc = __builtin_elementwise_fma(w23, xv[k][1], acc);   // v_pk_fma_f32
                acc = __builtin_elementwise_fma(w45, xv[k][2], acc);
                acc = __builtin_elementwise_fma(w67, xv[k][3], acc);
                const float u = acc[0] + acc[1];
                if (PASS == 0)
                    sacc2[k][c >> 1][c & 1] = fmaf(0.1f, u, sacc2[k][c >> 1][c & 1]);
                else
                    uh2[k][c >> 1][c & 1] = u;
            }
        }

        // ---- prefetch x for pp+1 (xv dead after dot phase; hides under softmax) ----
        if (pp + 1 < P_TILE) {
            const int pn = p0 + pp + 1;
            #pragma unroll
            for (int k = 0; k < K_B; ++k) {
                const float4* xq = reinterpret_cast<const float4*>(
                    x + ((size_t)bidx[k] * NP + pn) * NI);
                const float4 a = xq[0];
                const float4 b = xq[1];
                xv[k][0] = v2f{a.x, a.y};
                xv[k][1] = v2f{a.z, a.w};
                xv[k][2] = v2f{b.x, b.y};
                xv[k][3] = v2f{b.z, b.w};
            }
        }

        // ---- routing softmax + weighted accumulate ----
        if (PASS >= 1) {
            #pragma unroll
            for (int k = 0; k < K_B; ++k) {
                float lg[NC];
                #pragma unroll
                for (int c2 = 0; c2 < NC / 2; ++c2) {
                    const v2f pr = uh2[k][c2] * vr2[k][c2];            // v_pk_mul_f32
                    lg[2 * c2]     = red16_dpp(pr[0]);
                    lg[2 * c2 + 1] = red16_dpp(pr[1]);
                }
                v2f coup2[NC / 2];
                #pragma unroll
                for (int c2 = 0; c2 < NC / 2; ++c2) {
                    coup2[c2][0] = __builtin_amdgcn_exp2f(lg[2 * c2]);
                    coup2[c2][1] = __builtin_amdgcn_exp2f(lg[2 * c2 + 1]);
                }
                const v2f ss = (coup2[0] + coup2[1]) + (coup2[2] + coup2[3]) + coup2[4];
                const float inv = __builtin_amdgcn_rcpf(ss[0] + ss[1]);
                const v2f inv2 = {inv, inv};
                #pragma unroll
                for (int c2 = 0; c2 < NC / 2; ++c2)
                    sacc2[k][c2] = __builtin_elementwise_fma(
                        coup2[c2] * inv2, uh2[k][c2], sacc2[k][c2]);
            }
        }
    }

    // tail: each thread owns distinct (b,d) -> 10 atomics per k, no redundancy
    #pragma unroll
    for (int k = 0; k < K_B; ++k)
        #pragma unroll
        for (int c = 0; c < NC; ++c)
            atomicAdd(&s_out[(bidx[k] * NC + c) * ND + d], sacc2[k][c >> 1][c & 1]);
}

// v = (|s|^2/(1+|s|^2)) * s / sqrt(|s|^2+1e-7), norm over d (16-lane rows).
// ZERO_S: re-zero s for the next routing pass (replaces a hipMemsetAsync).
template<bool ZERO_S>
__global__ __launch_bounds__(256)
void caps_squash(float* __restrict__ s, float* __restrict__ v)
{
    const int idx = blockIdx.x * 256 + threadIdx.x;
    const float sv = s[idx];
    if (ZERO_S) s[idx] = 0.0f;
    float sq = red16_dpp(sv * sv);
    const float scale = (sq / (1.0f + sq)) / sqrtf(sq + 1e-7f);
    v[idx] = scale * sv;
}

extern "C" void kernel_launch(void* const* d_in, const int* in_sizes, int n_in,
                              void* d_out, int out_size, void* d_ws, size_t ws_size,
                              hipStream_t stream)
{
    const float* x = (const float*)d_in[0];
    const float* w = (const float*)d_in[1];
    float* out = (float*)d_out;

    float* s  = (float*)d_ws;       // [NB,NC,ND]
    float* v0 = s + SVD;            // [NB,NC,ND]
    float* v1 = out;                // reuse output buffer (overwritten by final squash)

    const dim3 pgrid(NBLK_B * NBLK_P);   // 2304 blocks of 256
    const dim3 pblock(256);
    const dim3 qgrid(SVD / 256);         // 320
    const dim3 qblock(256);

    hipMemsetAsync(s, 0, (size_t)SVD * sizeof(float), stream);
    caps_pass<0><<<pgrid, pblock, 0, stream>>>(x, w, nullptr, nullptr, s);
    caps_squash<true><<<qgrid, qblock, 0, stream>>>(s, v0);
    caps_pass<1><<<pgrid, pblock, 0, stream>>>(x, w, v0, nullptr, s);
    caps_squash<true><<<qgrid, qblock, 0, stream>>>(s, v1);
    caps_pass<2><<<pgrid, pblock, 0, stream>>>(x, w, v0, v1, s);
    caps_squash<false><<<qgrid, qblock, 0, stream>>>(s, out);
}

// Round 2
// 207.734 us; speedup vs baseline: 1.5839x; 1.5839x over previous
//
#include <hip/hip_runtime.h>
#include <hip/hip_bf16.h>

// Problem constants
#define NB 512     // batch
#define NP 1152    // primary capsules
#define NC 10      // digit capsules
#define ND 16      // output capsule dim
#define NI 8       // input capsule dim

constexpr int K_B    = 2;                // b's per lane (register loop) — 4 spilled (R5), 2 fits
constexpr int B_TILE = 4 * 4 * K_B;      // 32 b per block (4 waves x 4 bsub x K_B)
constexpr int P_TILE = 8;                // p's per block, LDS tile 40KB
constexpr int NBLK_B = NB / B_TILE;      // 16
constexpr int NBLK_P = NP / P_TILE;      // 144 (%8==0 -> XCD affinity: XCD = pblk%8)
constexpr int SVD = NB * NC * ND;        // 81920
constexpr int W_TILE_BYTES = P_TILE * NC * ND * NI * 4;   // 40960

constexpr float LOG2E = 1.4426950408889634f;

typedef float v2f __attribute__((ext_vector_type(2)));

// 16-lane all-reduce sum via DPP (quad_perm xor1, xor2; row_ror 4, 8).
// Pure VALU. Result broadcast to all 16 lanes of the row.
__device__ __forceinline__ float red16_dpp(float v) {
    int t;
    t = __builtin_amdgcn_update_dpp(0, __float_as_int(v), 0xB1, 0xF, 0xF, true); // xor1
    v += __int_as_float(t);
    t = __builtin_amdgcn_update_dpp(0, __float_as_int(v), 0x4E, 0xF, 0xF, true); // xor2
    v += __int_as_float(t);
    t = __builtin_amdgcn_update_dpp(0, __float_as_int(v), 0x124, 0xF, 0xF, true); // row_ror:4
    v += __int_as_float(t);
    t = __builtin_amdgcn_update_dpp(0, __float_as_int(v), 0x128, 0xF, 0xF, true); // row_ror:8
    v += __int_as_float(t);
    return v;
}

// One routing pass (R3 skeleton + K_B=2 + both-sides swizzle + pk-fma dots).
// 4 waves/block; each wave stages one LDS quarter, ALL waves read all 8 p's
// for their own 8 b's (wave*8 + k*4 + bsub). Lane = (bsub 2b | d 4b).
// LDS swizzle involution: S(A) = A ^ (bit7(A)<<4) ^ (bit8(A)<<5).
// Staging: LDS linear dest L <- global source S(L). Reads: issue S(A).
// Softmax slimming (R1, numerics verified): log2(e) folded into vr at load,
// NO max-subtraction (|lg*log2e| <~ 50 << 127, exp2-safe), v_rcp_f32 for 1/sum.
// Structure otherwise identical to the verified 214.7us kernel (R1's v2f
// repack + x-prefetch restructure caused scratch spills: FETCH/WRITE x20).
// PASS 0: coup = 0.1;  PASS 1: logits = u.v0;  PASS 2: logits = u.(v0+v1)
template<int PASS>
__global__ __launch_bounds__(256, 3)
void caps_pass(const float* __restrict__ x,    // [NB, NP, NI]
               const float* __restrict__ w,    // [NP, NC, ND, NI]
               const float* __restrict__ v0,   // [NB, NC, ND]
               const float* __restrict__ v1,   // [NB, NC, ND]
               float* __restrict__ s_out)      // [NB, NC, ND]
{
    __shared__ __align__(16) float w_lds[W_TILE_BYTES / 4];   // 40KB

    const int tid  = threadIdx.x;
    const int lane = tid & 63;
    const int wave = tid >> 6;           // 0..3
    const int d    = lane & 15;
    const int bsub = lane >> 4;          // 0..3
    const int pblk = blockIdx.x % NBLK_P;
    const int bblk = blockIdx.x / NBLK_P;
    const int p0   = pblk * P_TILE;

    // ---- stage W tile: each wave loads one 10KB quarter (16B/lane, linear dest) ----
    {
        const uint8_t* wsrc = (const uint8_t*)w + (size_t)pblk * W_TILE_BYTES;
        // source offset: S(lane*16) within the 1KB chunk (bits 7,8 of chunk bases are 0)
        const int lane_src = (lane << 4) ^ ((lane & 8) << 1) ^ ((lane & 16) << 1);
        #pragma unroll
        for (int j = 0; j < 10; ++j) {
            const int off = wave * 10240 + j * 1024;
            __builtin_amdgcn_global_load_lds(
                (const __attribute__((address_space(1))) void*)(wsrc + off + lane_src),
                (__attribute__((address_space(3))) void*)((uint8_t*)w_lds + off),
                16, 0, 0);
        }
    }

    int bidx[K_B];
    #pragma unroll
    for (int k = 0; k < K_B; ++k) bidx[k] = bblk * B_TILE + wave * 8 + k * 4 + bsub;

    // v (v0, or v0+v1 for pass 2), pre-scaled by log2(e) — loop-invariant over p
    float vr[K_B][NC];
    if (PASS >= 1) {
        #pragma unroll
        for (int k = 0; k < K_B; ++k)
            #pragma unroll
            for (int c = 0; c < NC; ++c) {
                float vv = v0[(bidx[k] * NC + c) * ND + d];
                if (PASS == 2) vv += v1[(bidx[k] * NC + c) * ND + d];
                vr[k][c] = vv * LOG2E;
            }
    }

    float sacc[K_B][NC];
    #pragma unroll
    for (int k = 0; k < K_B; ++k)
        #pragma unroll
        for (int c = 0; c < NC; ++c) sacc[k][c] = 0.0f;

    // swizzled read offset for W[pp,c,d,0:4]: A = d*32 -> A ^ (bit2(d)<<4) ^ (bit3(d)<<5).
    // Half 2 at A+16 = lane_rd^16 (bit4 flip, bits 7,8 unchanged).
    const int lane_rd = (d << 5) ^ ((d & 4) << 2) ^ ((d & 8) << 2);

    asm volatile("s_waitcnt vmcnt(0)" ::: "memory");   // staging complete
    __syncthreads();                                   // all quarters visible to all waves

    for (int pp = 0; pp < P_TILE; ++pp) {
        const int p = p0 + pp;

        v2f xv[K_B][4];
        #pragma unroll
        for (int k = 0; k < K_B; ++k) {
            const float4* xq = reinterpret_cast<const float4*>(
                x + ((size_t)bidx[k] * NP + p) * NI);
            const float4 a = xq[0];
            const float4 b = xq[1];
            xv[k][0] = v2f{a.x, a.y};
            xv[k][1] = v2f{a.z, a.w};
            xv[k][2] = v2f{b.x, b.y};
            xv[k][3] = v2f{b.z, b.w};
        }

        float uh[K_B][NC];
        #pragma unroll
        for (int c = 0; c < NC; ++c) {
            const uint8_t* pb = (const uint8_t*)w_lds + pp * 5120 + c * 512;
            const float4 wa = *(const float4*)(pb + lane_rd);          // W[p,c,d,0:4]
            const float4 wb = *(const float4*)(pb + (lane_rd ^ 16));   // W[p,c,d,4:8]
            const v2f w01{wa.x, wa.y}, w23{wa.z, wa.w};
            const v2f w45{wb.x, wb.y}, w67{wb.z, wb.w};
            #pragma unroll
            for (int k = 0; k < K_B; ++k) {
                v2f acc = w01 * xv[k][0];                              // v_pk_mul_f32
                acc = __builtin_elementwise_fma(w23, xv[k][1], acc);   // v_pk_fma_f32
                acc = __builtin_elementwise_fma(w45, xv[k][2], acc);
                acc = __builtin_elementwise_fma(w67, xv[k][3], acc);
                const float u = acc[0] + acc[1];
                if (PASS == 0) sacc[k][c] = fmaf(0.1f, u, sacc[k][c]);
                else           uh[k][c] = u;
            }
        }

        if (PASS >= 1) {
            #pragma unroll
            for (int k = 0; k < K_B; ++k) {
                float lg[NC];
                #pragma unroll
                for (int c = 0; c < NC; ++c)
                    lg[c] = red16_dpp(uh[k][c] * vr[k][c]);   // log2-domain logits
                float ssum = 0.0f;
                float coup[NC];
                #pragma unroll
                for (int c = 0; c < NC; ++c) {
                    coup[c] = __builtin_amdgcn_exp2f(lg[c]);  // no max-sub: bounded
                    ssum += coup[c];
                }
                const float inv = __builtin_amdgcn_rcpf(ssum);
                #pragma unroll
                for (int c = 0; c < NC; ++c)
                    sacc[k][c] = fmaf(coup[c] * inv, uh[k][c], sacc[k][c]);
            }
        }
    }

    // tail: each thread owns distinct (b,d) -> 10 atomics per k, no redundancy
    #pragma unroll
    for (int k = 0; k < K_B; ++k)
        #pragma unroll
        for (int c = 0; c < NC; ++c)
            atomicAdd(&s_out[(bidx[k] * NC + c) * ND + d], sacc[k][c]);
}

// v = (|s|^2/(1+|s|^2)) * s / sqrt(|s|^2+1e-7), norm over d (16-lane rows).
// ZERO_S: re-zero s for the next routing pass (replaces a hipMemsetAsync).
template<bool ZERO_S>
__global__ __launch_bounds__(256)
void caps_squash(float* __restrict__ s, float* __restrict__ v)
{
    const int idx = blockIdx.x * 256 + threadIdx.x;
    const float sv = s[idx];
    if (ZERO_S) s[idx] = 0.0f;
    float sq = red16_dpp(sv * sv);
    const float scale = (sq / (1.0f + sq)) / sqrtf(sq + 1e-7f);
    v[idx] = scale * sv;
}

extern "C" void kernel_launch(void* const* d_in, const int* in_sizes, int n_in,
                              void* d_out, int out_size, void* d_ws, size_t ws_size,
                              hipStream_t stream)
{
    const float* x = (const float*)d_in[0];
    const float* w = (const float*)d_in[1];
    float* out = (float*)d_out;

    float* s  = (float*)d_ws;       // [NB,NC,ND]
    float* v0 = s + SVD;            // [NB,NC,ND]
    float* v1 = out;                // reuse output buffer (overwritten by final squash)

    const dim3 pgrid(NBLK_B * NBLK_P);   // 2304 blocks of 256
    const dim3 pblock(256);
    const dim3 qgrid(SVD / 256);         // 320
    const dim3 qblock(256);

    hipMemsetAsync(s, 0, (size_t)SVD * sizeof(float), stream);
    caps_pass<0><<<pgrid, pblock, 0, stream>>>(x, w, nullptr, nullptr, s);
    caps_squash<true><<<qgrid, qblock, 0, stream>>>(s, v0);
    caps_pass<1><<<pgrid, pblock, 0, stream>>>(x, w, v0, nullptr, s);
    caps_squash<true><<<qgrid, qblock, 0, stream>>>(s, v1);
    caps_pass<2><<<pgrid, pblock, 0, stream>>>(x, w, v0, v1, s);
    caps_squash<false><<<qgrid, qblock, 0, stream>>>(s, out);
}

// Round 3
// 190.098 us; speedup vs baseline: 1.7308x; 1.0928x over previous
//
#include <hip/hip_runtime.h>
#include <hip/hip_bf16.h>

// Problem constants
#define NB 512     // batch
#define NP 1152    // primary capsules
#define NC 10      // digit capsules
#define ND 16      // output capsule dim
#define NI 8       // input capsule dim

constexpr int K_B    = 2;                // b's per lane (register loop) — 4 spilled (R5), 2 fits
constexpr int B_TILE = 4 * 4 * K_B;      // 32 b per block (4 waves x 4 bsub x K_B)
constexpr int P_TILE = 8;                // p's per block, LDS tile 40KB
constexpr int NBLK_B = NB / B_TILE;      // 16
constexpr int NBLK_P = NP / P_TILE;      // 144 (%8==0 -> XCD affinity: XCD = pblk%8)
constexpr int SVD = NB * NC * ND;        // 81920
constexpr int W_TILE_BYTES = P_TILE * NC * ND * NI * 4;   // 40960
constexpr int X_TILE_FLOATS = B_TILE * P_TILE * NI;       // 2048 floats = 8KB

constexpr float LOG2E = 1.4426950408889634f;

typedef float v2f __attribute__((ext_vector_type(2)));

// 16-lane all-reduce sum via DPP (quad_perm xor1, xor2; row_ror 4, 8).
// Pure VALU. Result broadcast to all 16 lanes of the row.
__device__ __forceinline__ float red16_dpp(float v) {
    int t;
    t = __builtin_amdgcn_update_dpp(0, __float_as_int(v), 0xB1, 0xF, 0xF, true); // xor1
    v += __int_as_float(t);
    t = __builtin_amdgcn_update_dpp(0, __float_as_int(v), 0x4E, 0xF, 0xF, true); // xor2
    v += __int_as_float(t);
    t = __builtin_amdgcn_update_dpp(0, __float_as_int(v), 0x124, 0xF, 0xF, true); // row_ror:4
    v += __int_as_float(t);
    t = __builtin_amdgcn_update_dpp(0, __float_as_int(v), 0x128, 0xF, 0xF, true); // row_ror:8
    v += __int_as_float(t);
    return v;
}

// One routing pass. 4 waves/block; each wave stages one LDS quarter of W plus
// 2KB of x, ALL waves read all 8 p's for their own 8 b's (wave*8 + k*4 + bsub).
// Lane = (bsub 2b | d 4b).
// W LDS swizzle involution: S(A) = A ^ (bit7(A)<<4) ^ (bit8(A)<<5).
// Staging: LDS linear dest L <- global source S(L). Reads: issue S(A).
// x is ALSO staged in LDS (R3 change): the block's x working set is only 8KB
// (32 b x 8 p x 8 i); per-iteration global x loads (HBM latency, unhidden at
// 2.1 waves/SIMD) were the ~77us floor — pass0 == pass1 duration proved the
// bottleneck was not VALU. Main loop is now LDS+VALU only.
// Softmax slimming (R2, verified): log2(e) folded into vr, NO max-subtraction
// (|lg*log2e| <~ 50 << 127, exp2-safe), v_rcp_f32 for 1/sum.
// PASS 0: coup = 0.1;  PASS 1: logits = u.v0;  PASS 2: logits = u.(v0+v1)
template<int PASS>
__global__ __launch_bounds__(256, 3)
void caps_pass(const float* __restrict__ x,    // [NB, NP, NI]
               const float* __restrict__ w,    // [NP, NC, ND, NI]
               const float* __restrict__ v0,   // [NB, NC, ND]
               const float* __restrict__ v1,   // [NB, NC, ND]
               float* __restrict__ s_out)      // [NB, NC, ND]
{
    __shared__ __align__(16) float w_lds[W_TILE_BYTES / 4];   // 40KB
    __shared__ __align__(16) float x_lds[X_TILE_FLOATS];      // 8KB, [b_local][pp][i]

    const int tid  = threadIdx.x;
    const int lane = tid & 63;
    const int wave = tid >> 6;           // 0..3
    const int d    = lane & 15;
    const int bsub = lane >> 4;          // 0..3
    const int pblk = blockIdx.x % NBLK_P;
    const int bblk = blockIdx.x / NBLK_P;
    const int p0   = pblk * P_TILE;

    // ---- stage W tile: each wave loads one 10KB quarter (16B/lane, linear dest) ----
    {
        const uint8_t* wsrc = (const uint8_t*)w + (size_t)pblk * W_TILE_BYTES;
        // source offset: S(lane*16) within the 1KB chunk (bits 7,8 of chunk bases are 0)
        const int lane_src = (lane << 4) ^ ((lane & 8) << 1) ^ ((lane & 16) << 1);
        #pragma unroll
        for (int j = 0; j < 10; ++j) {
            const int off = wave * 10240 + j * 1024;
            __builtin_amdgcn_global_load_lds(
                (const __attribute__((address_space(1))) void*)(wsrc + off + lane_src),
                (__attribute__((address_space(3))) void*)((uint8_t*)w_lds + off),
                16, 0, 0);
        }
    }

    // ---- stage x tile: 8KB, linear LDS dest, strided global source ----
    // 16B unit u (0..511): b_local = u>>4, pp = (u>>1)&7, half = u&1.
    // Source = x[bblk*32 + b_local][p0 + pp][half*4 ..], a 256B strip per
    // 16-lane group — per-lane source is allowed, dest is uniform + lane*16.
    {
        #pragma unroll
        for (int j = 0; j < 2; ++j) {
            const int u    = (wave * 2 + j) * 64 + lane;
            const int bl   = u >> 4;
            const int ppu  = (u >> 1) & 7;
            const int half = u & 1;
            const float* src = x + ((size_t)(bblk * B_TILE + bl) * NP + p0 + ppu) * NI
                                 + half * 4;
            __builtin_amdgcn_global_load_lds(
                (const __attribute__((address_space(1))) void*)src,
                (__attribute__((address_space(3))) void*)((uint8_t*)x_lds + (size_t)u * 16),
                16, 0, 0);
        }
    }

    int bidx[K_B];
    #pragma unroll
    for (int k = 0; k < K_B; ++k) bidx[k] = bblk * B_TILE + wave * 8 + k * 4 + bsub;

    // v (v0, or v0+v1 for pass 2), pre-scaled by log2(e) — loop-invariant over p
    float vr[K_B][NC];
    if (PASS >= 1) {
        #pragma unroll
        for (int k = 0; k < K_B; ++k)
            #pragma unroll
            for (int c = 0; c < NC; ++c) {
                float vv = v0[(bidx[k] * NC + c) * ND + d];
                if (PASS == 2) vv += v1[(bidx[k] * NC + c) * ND + d];
                vr[k][c] = vv * LOG2E;
            }
    }

    float sacc[K_B][NC];
    #pragma unroll
    for (int k = 0; k < K_B; ++k)
        #pragma unroll
        for (int c = 0; c < NC; ++c) sacc[k][c] = 0.0f;

    // swizzled read offset for W[pp,c,d,0:4]: A = d*32 -> A ^ (bit2(d)<<4) ^ (bit3(d)<<5).
    // Half 2 at A+16 = lane_rd^16 (bit4 flip, bits 7,8 unchanged).
    const int lane_rd = (d << 5) ^ ((d & 4) << 2) ^ ((d & 8) << 2);

    asm volatile("s_waitcnt vmcnt(0)" ::: "memory");   // W + x staging complete
    __syncthreads();                                   // all quarters visible to all waves

    for (int pp = 0; pp < P_TILE; ++pp) {
        v2f xv[K_B][4];
        #pragma unroll
        for (int k = 0; k < K_B; ++k) {
            const float4* xq = reinterpret_cast<const float4*>(
                x_lds + (wave * 8 + k * 4 + bsub) * (P_TILE * NI) + pp * NI);
            const float4 a = xq[0];
            const float4 b = xq[1];
            xv[k][0] = v2f{a.x, a.y};
            xv[k][1] = v2f{a.z, a.w};
            xv[k][2] = v2f{b.x, b.y};
            xv[k][3] = v2f{b.z, b.w};
        }

        float uh[K_B][NC];
        #pragma unroll
        for (int c = 0; c < NC; ++c) {
            const uint8_t* pb = (const uint8_t*)w_lds + pp * 5120 + c * 512;
            const float4 wa = *(const float4*)(pb + lane_rd);          // W[p,c,d,0:4]
            const float4 wb = *(const float4*)(pb + (lane_rd ^ 16));   // W[p,c,d,4:8]
            const v2f w01{wa.x, wa.y}, w23{wa.z, wa.w};
            const v2f w45{wb.x, wb.y}, w67{wb.z, wb.w};
            #pragma unroll
            for (int k = 0; k < K_B; ++k) {
                v2f acc = w01 * xv[k][0];                              // v_pk_mul_f32
                acc = __builtin_elementwise_fma(w23, xv[k][1], acc);   // v_pk_fma_f32
                acc = __builtin_elementwise_fma(w45, xv[k][2], acc);
                acc = __builtin_elementwise_fma(w67, xv[k][3], acc);
                const float u = acc[0] + acc[1];
                if (PASS == 0) sacc[k][c] = fmaf(0.1f, u, sacc[k][c]);
                else           uh[k][c] = u;
            }
        }

        if (PASS >= 1) {
            #pragma unroll
            for (int k = 0; k < K_B; ++k) {
                float lg[NC];
                #pragma unroll
                for (int c = 0; c < NC; ++c)
                    lg[c] = red16_dpp(uh[k][c] * vr[k][c]);   // log2-domain logits
                float ssum = 0.0f;
                float coup[NC];
                #pragma unroll
                for (int c = 0; c < NC; ++c) {
                    coup[c] = __builtin_amdgcn_exp2f(lg[c]);  // no max-sub: bounded
                    ssum += coup[c];
                }
                const float inv = __builtin_amdgcn_rcpf(ssum);
                #pragma unroll
                for (int c = 0; c < NC; ++c)
                    sacc[k][c] = fmaf(coup[c] * inv, uh[k][c], sacc[k][c]);
            }
        }
    }

    // tail: each thread owns distinct (b,d) -> 10 atomics per k, no redundancy
    #pragma unroll
    for (int k = 0; k < K_B; ++k)
        #pragma unroll
        for (int c = 0; c < NC; ++c)
            atomicAdd(&s_out[(bidx[k] * NC + c) * ND + d], sacc[k][c]);
}

// v = (|s|^2/(1+|s|^2)) * s / sqrt(|s|^2+1e-7), norm over d (16-lane rows).
// ZERO_S: re-zero s for the next routing pass (replaces a hipMemsetAsync).
template<bool ZERO_S>
__global__ __launch_bounds__(256)
void caps_squash(float* __restrict__ s, float* __restrict__ v)
{
    const int idx = blockIdx.x * 256 + threadIdx.x;
    const float sv = s[idx];
    if (ZERO_S) s[idx] = 0.0f;
    float sq = red16_dpp(sv * sv);
    const float scale = (sq / (1.0f + sq)) / sqrtf(sq + 1e-7f);
    v[idx] = scale * sv;
}

extern "C" void kernel_launch(void* const* d_in, const int* in_sizes, int n_in,
                              void* d_out, int out_size, void* d_ws, size_t ws_size,
                              hipStream_t stream)
{
    const float* x = (const float*)d_in[0];
    const float* w = (const float*)d_in[1];
    float* out = (float*)d_out;

    float* s  = (float*)d_ws;       // [NB,NC,ND]
    float* v0 = s + SVD;            // [NB,NC,ND]
    float* v1 = out;                // reuse output buffer (overwritten by final squash)

    const dim3 pgrid(NBLK_B * NBLK_P);   // 2304 blocks of 256
    const dim3 pblock(256);
    const dim3 qgrid(SVD / 256);         // 320
    const dim3 qblock(256);

    hipMemsetAsync(s, 0, (size_t)SVD * sizeof(float), stream);
    caps_pass<0><<<pgrid, pblock, 0, stream>>>(x, w, nullptr, nullptr, s);
    caps_squash<true><<<qgrid, qblock, 0, stream>>>(s, v0);
    caps_pass<1><<<pgrid, pblock, 0, stream>>>(x, w, v0, nullptr, s);
    caps_squash<true><<<qgrid, qblock, 0, stream>>>(s, v1);
    caps_pass<2><<<pgrid, pblock, 0, stream>>>(x, w, v0, v1, s);
    caps_squash<false><<<qgrid, qblock, 0, stream>>>(s, out);
}